// Round 11
// baseline (447.081 us; speedup 1.0000x reference)
//
#include <hip/hip_runtime.h>
#include <hip/hip_bf16.h>
#include <math.h>

typedef __attribute__((ext_vector_type(8))) short bh8;
typedef __attribute__((ext_vector_type(4))) short sh4;
typedef __attribute__((ext_vector_type(4))) float fx4;

__device__ __forceinline__ fx4 mfma_bf16(bh8 a, bh8 b, fx4 c) {
    return __builtin_amdgcn_mfma_f32_16x16x32_bf16(a, b, c, 0, 0, 0);
}

// async global->LDS, 16B per lane. LDS dest = wave-uniform base + lane*16.
__device__ __forceinline__ void gload16(const __hip_bfloat16* g, __hip_bfloat16* l) {
    __builtin_amdgcn_global_load_lds(
        (const __attribute__((address_space(1))) void*)g,
        (__attribute__((address_space(3))) void*)l,
        16, 0, 0);
}

// branchless erf, Abramowitz-Stegun 7.1.26, |abs err| <= 1.5e-7 (<< bf16 rounding).
__device__ __forceinline__ float fast_erf(float u) {
    float au = fabsf(u);
    float t  = __builtin_amdgcn_rcpf(1.0f + 0.3275911f * au);
    float p  = ((((1.061405429f * t - 1.453152027f) * t + 1.421413741f) * t
                 - 0.284496736f) * t + 0.254829592f) * t;
    float e  = __expf(-u * u);
    return copysignf(1.0f - p * e, u);
}

__device__ __forceinline__ short bf16s(float f) {
    union { __hip_bfloat16 h; short s; } u;
    u.h = __float2bfloat16(f);
    return u.s;
}

// sync/wait primitives (T4 counted-vmcnt, m218). sched_barrier(0) after each
// asm wait: hipcc hoists register-only MFMA past inline-asm waitcnt (rule #18).
#define WAITV6 do { asm volatile("s_waitcnt vmcnt(6)" ::: "memory"); \
                    __builtin_amdgcn_sched_barrier(0); } while (0)
#define WAITV0 do { asm volatile("s_waitcnt vmcnt(0)" ::: "memory"); \
                    __builtin_amdgcn_sched_barrier(0); } while (0)
#define LGKM0  do { asm volatile("s_waitcnt lgkmcnt(0)" ::: "memory"); \
                    __builtin_amdgcn_sched_barrier(0); } while (0)
#define BARR   do { __builtin_amdgcn_s_barrier(); \
                    __builtin_amdgcn_sched_barrier(0); } while (0)

// ---------------- merged weight convert+transpose (one launch for all 4) ----------------
// qkv 192x576=110592 | proj 192x192=36864 | fc1 192x768=147456 | fc2 768x192=147456
__global__ __launch_bounds__(256)
void convw_all_k(const float* __restrict__ qkv_w, const float* __restrict__ proj_w,
                 const float* __restrict__ fc1_w, const float* __restrict__ fc2_w,
                 __hip_bfloat16* __restrict__ wq, __hip_bfloat16* __restrict__ wp,
                 __hip_bfloat16* __restrict__ w1, __hip_bfloat16* __restrict__ w2)
{
    int idx = blockIdx.x * 256 + threadIdx.x;
    if (idx < 110592) {
        int k = idx / 576, n = idx - k * 576;
        wq[(size_t)n * 192 + k] = __float2bfloat16(qkv_w[idx]);
        return;
    }
    idx -= 110592;
    if (idx < 36864) {
        int k = idx / 192, n = idx - k * 192;
        wp[(size_t)n * 192 + k] = __float2bfloat16(proj_w[idx]);
        return;
    }
    idx -= 36864;
    if (idx < 147456) {
        int k = idx / 768, n = idx - k * 768;
        w1[(size_t)n * 192 + k] = __float2bfloat16(fc1_w[idx]);
        return;
    }
    idx -= 147456;
    if (idx < 147456) {
        int k = idx / 192, n = idx - k * 192;
        w2[(size_t)n * 768 + k] = __float2bfloat16(fc2_w[idx]);
    }
}

// ---------------- fused LN1 + shift/gather + QKV GEMM ----------------
// 64 window-ordered tokens per block (grid 1568, exact). LN head: 4 threads/row,
// each loads 48 contiguous fp32 (12x fx4), 2-level shfl_xor reduce, writes
// normalized bf16 into the chunked Xs[6][64][32] LDS tile (the standard
// conflict-free GEMM layout). Then 9 output col-blocks: stage B chunk
// (64x192 -> Bs[6][64][32], mlp's gload16 pattern), K=192 MFMA, epilogue with
// bias (+SCALE on q cols). Kills the 38.5MB xw tensor round-trip + 1 dispatch.
__global__ __launch_bounds__(256)
void lnqkv_k(const float* __restrict__ x, const float* __restrict__ g,
             const float* __restrict__ bia,
             const __hip_bfloat16* __restrict__ Bt,   // wt_qkv [576][192]
             const float* __restrict__ qb,
             __hip_bfloat16* __restrict__ outv)       // [100352][576] bf16
{
    __shared__ __align__(16) __hip_bfloat16 Xs[6][64][32];  // 24.6 KB
    __shared__ __align__(16) __hip_bfloat16 Bs[6][64][32];  // 24.6 KB

    const int tid  = threadIdx.x;
    const int lane = tid & 63, wave = tid >> 6;
    const int quad = lane >> 4, l15 = lane & 15;
    const int m0 = blockIdx.x * 64;
    const int arow = lane >> 2, acol = (lane & 3) * 8;

    // ---- LN + shift + window gather -> Xs ----
    {
        const int r = tid >> 2, c = tid & 3;      // 4 threads per token row
        const int t = m0 + r;
        const int w = t / 49, n = t - w * 49;
        const int b = w >> 6, wrem = w & 63, wi = wrem >> 3, wj = wrem & 7;
        const int i = n / 7, j = n - i * 7;
        int sr = wi * 7 + i + 3; if (sr >= 56) sr -= 56;
        int sc = wj * 7 + j + 3; if (sc >= 56) sc -= 56;
        const float* xp = x + ((size_t)b * 3136 + sr * 56 + sc) * 192 + c * 48;

        fx4 v[12];
        float s = 0.f, q = 0.f;
#pragma unroll
        for (int u = 0; u < 12; u++) {
            v[u] = *(const fx4*)(xp + u * 4);
            s += v[u][0] + v[u][1] + v[u][2] + v[u][3];
            q += v[u][0]*v[u][0] + v[u][1]*v[u][1] + v[u][2]*v[u][2] + v[u][3]*v[u][3];
        }
        s += __shfl_xor(s, 1, 64);  q += __shfl_xor(q, 1, 64);
        s += __shfl_xor(s, 2, 64);  q += __shfl_xor(q, 2, 64);
        float mean = s * (1.0f / 192.0f);
        float var  = q * (1.0f / 192.0f) - mean * mean;
        float rstd = rsqrtf(var + 1e-5f);

#pragma unroll
        for (int jj = 0; jj < 6; jj++) {          // 8 elems per group
            const int col = c * 48 + jj * 8;
            const fx4 g0 = *(const fx4*)(g + col),     g1 = *(const fx4*)(g + col + 4);
            const fx4 b0 = *(const fx4*)(bia + col),   b1 = *(const fx4*)(bia + col + 4);
            union { short sh[8]; bh8 v8; } pk;
#pragma unroll
            for (int e = 0; e < 4; e++) {
                const int f0 = jj * 8 + e, f1 = jj * 8 + 4 + e;
                pk.sh[e]     = bf16s((v[f0 >> 2][f0 & 3] - mean) * rstd * g0[e] + b0[e]);
                pk.sh[e + 4] = bf16s((v[f1 >> 2][f1 & 3] - mean) * rstd * g1[e] + b1[e]);
            }
            *(bh8*)&Xs[col >> 5][r][col & 31] = pk.v8;
        }
    }

    // ---- 9 output col-blocks of 64 ----
    for (int nb = 0; nb < 9; nb++) {
        // stage B chunk: 24 gloads (6 kc x 4 segs of 16 rows), 6 per wave
#pragma unroll
        for (int i2 = 0; i2 < 6; i2++) {
            const int gi = wave * 6 + i2;          // 0..23
            const int kc = gi >> 2, seg = gi & 3;
            gload16(Bt + (size_t)(nb * 64 + seg * 16 + arow) * 192 + kc * 32 + acol,
                    &Bs[kc][seg * 16][0]);
        }
        __syncthreads();   // drains staging vmcnt (+ Xs lgkm writes on first iter)

        fx4 acc[4];
#pragma unroll
        for (int ni = 0; ni < 4; ni++) acc[ni] = {0.f, 0.f, 0.f, 0.f};
#pragma unroll
        for (int kc = 0; kc < 6; kc++) {
            bh8 a = *(const bh8*)&Xs[kc][wave * 16 + l15][quad * 8];
#pragma unroll
            for (int ni = 0; ni < 4; ni++) {
                bh8 bfrag = *(const bh8*)&Bs[kc][ni * 16 + l15][quad * 8];
                acc[ni] = mfma_bf16(a, bfrag, acc[ni]);
            }
        }

#pragma unroll
        for (int ni = 0; ni < 4; ni++) {
            const int n = nb * 64 + ni * 16 + l15;
            const float bn = qb[n];
#pragma unroll
            for (int r = 0; r < 4; r++) {
                const int m = m0 + wave * 16 + quad * 4 + r;
                float val = acc[ni][r] + bn;
                if (n < 192) val *= 0.17677669529663687f;   // SCALE on q
                outv[(size_t)m * 576 + n] = __float2bfloat16(val);
            }
        }
        __syncthreads();   // all waves done reading Bs; safe to restage
    }
}

// ---------------- fused MLP (R4-exact, best measured: 148 us) ----------------
// See R9 notes: register-capped at 2 waves/SIMD; 5 restructures all >= 148.
__global__ __launch_bounds__(256, 2)
void mlp_k(const __hip_bfloat16* __restrict__ A,      // y2 [100352][192] bf16
           const __hip_bfloat16* __restrict__ W1t,    // [768][192] bf16 (n-major)
           const __hip_bfloat16* __restrict__ W2t,    // [192][768] bf16 (n-major)
           const float* __restrict__ b1,
           const float* __restrict__ b2,
           float* __restrict__ out)                   // x1, in-place += mlp
{
    __shared__ __align__(16) __hip_bfloat16 W1s[2][6][32][32];  // 24 KB
    __shared__ __align__(16) __hip_bfloat16 W2s[2][192][32];    // 24 KB
    __shared__ __align__(16) __hip_bfloat16 Hs[128][40];        // 10 KB, 80B stride
    __shared__ __align__(16) float b1s[768];                    // 3 KB

    const int tid  = threadIdx.x;
    const int lane = tid & 63, wave = tid >> 6;
    const int quad = lane >> 4, l15 = lane & 15;
    const int m0 = blockIdx.x * 128;
    const int arow = lane >> 2, acol = (lane & 3) * 8;

    // b1 -> LDS once (192 threads x 16B). Drain ds_write before first barrier.
    if (tid < 192) ((fx4*)b1s)[tid] = ((const fx4*)b1)[tid];
    LGKM0;

    // X fragments in registers: 2 row-tiles x 6 k-chunks (48 VGPR).
    bh8 xr[2][6];
    const __hip_bfloat16* xg = A + (size_t)(m0 + wave * 32 + l15) * 192 + quad * 8;
#pragma unroll
    for (int rt = 0; rt < 2; rt++)
#pragma unroll
        for (int kc = 0; kc < 6; kc++)
            xr[rt][kc] = *(const bh8*)(xg + rt * 16 * 192 + kc * 32);

    // stage one 32-hidden chunk: W1 (32x192) + W2 (192x32), 6 gloads/wave.
    auto stage = [&](int bf, int c) {
#pragma unroll
        for (int i = 0; i < 3; i++) {
            const int g = wave * 3 + i;
            const int kc = g >> 1, half = g & 1;
            gload16(W1t + (size_t)(c * 32 + half * 16 + arow) * 192 + kc * 32 + acol,
                    &W1s[bf][kc][half * 16][0]);
            gload16(W2t + (size_t)(g * 16 + arow) * 768 + c * 32 + acol,
                    &W2s[bf][g * 16][0]);
        }
    };

    fx4 acc2[2][12];
#pragma unroll
    for (int rt = 0; rt < 2; rt++)
#pragma unroll
        for (int nt = 0; nt < 12; nt++) acc2[rt][nt] = {0.f, 0.f, 0.f, 0.f};

    stage(0, 0);
    stage(1, 1);

    int cur = 0;
    for (int c = 0; c < 23; ++c) {
        WAITV6;            // my chunk-c stage done; chunk-(c+1)'s 6 ops stay in flight
        BARR;              // all waves' chunk-c loads landed in buf[cur]

        // bias frags for this chunk (hidden-major: 4 consecutive h per reg)
        fx4 bv0 = *(const fx4*)&b1s[c * 32 + quad * 4];
        fx4 bv1 = *(const fx4*)&b1s[c * 32 + 16 + quad * 4];

        // ---- FC1 swapped: acc1[rt][ni] = H^T tile, K=192, X from registers ----
        fx4 acc1[2][2];
        acc1[0][0] = {0.f, 0.f, 0.f, 0.f}; acc1[0][1] = {0.f, 0.f, 0.f, 0.f};
        acc1[1][0] = {0.f, 0.f, 0.f, 0.f}; acc1[1][1] = {0.f, 0.f, 0.f, 0.f};
        __builtin_amdgcn_s_setprio(1);
#pragma unroll
        for (int kc = 0; kc < 6; kc++) {
#pragma unroll
            for (int ni = 0; ni < 2; ni++) {
                bh8 w = *(const bh8*)&W1s[cur][kc][ni * 16 + l15][quad * 8];
                acc1[0][ni] = mfma_bf16(w, xr[0][kc], acc1[0][ni]);
                acc1[1][ni] = mfma_bf16(w, xr[1][kc], acc1[1][ni]);
            }
        }
        __builtin_amdgcn_s_setprio(0);

        // ---- bias + gelu + pack -> Hs[m][h] (one b64 write per tile) ----
#pragma unroll
        for (int rt = 0; rt < 2; rt++) {
#pragma unroll
            for (int ni = 0; ni < 2; ni++) {
                const fx4 bv = ni ? bv1 : bv0;
                sh4 pk;
#pragma unroll
                for (int r = 0; r < 4; r++) {
                    float v = acc1[rt][ni][r] + bv[r];
                    float h = 0.5f * v * (1.0f + fast_erf(v * 0.70710678118654752f));
                    pk[r] = bf16s(h);
                }
                *(sh4*)&Hs[wave * 32 + rt * 16 + l15][ni * 16 + quad * 4] = pk;
            }
        }
        LGKM0;             // wave-private Hs write->read handoff (no vm drain)

        // ---- FC2: acc2 += H-chunk @ W2-chunk (K=32) ----
        bh8 ha0 = *(const bh8*)&Hs[wave * 32 + l15][quad * 8];
        bh8 ha1 = *(const bh8*)&Hs[wave * 32 + 16 + l15][quad * 8];
        __builtin_amdgcn_s_setprio(1);
#pragma unroll
        for (int nt = 0; nt < 12; nt++) {
            bh8 w2 = *(const bh8*)&W2s[cur][nt * 16 + l15][quad * 8];
            acc2[0][nt] = mfma_bf16(ha0, w2, acc2[0][nt]);
            acc2[1][nt] = mfma_bf16(ha1, w2, acc2[1][nt]);
        }
        __builtin_amdgcn_s_setprio(0);

        BARR;              // all waves done reading buf[cur]; safe to restage it
        if (c < 22) stage(cur, c + 2);
        cur ^= 1;
    }

    // ---- peeled chunk 23 (drain once) ----
    {
        WAITV0;
        BARR;
        fx4 bv0 = *(const fx4*)&b1s[23 * 32 + 0 * 16 + quad * 4];
        fx4 bv1 = *(const fx4*)&b1s[23 * 32 + 1 * 16 + quad * 4];
        fx4 acc1[2][2];
        acc1[0][0] = {0.f, 0.f, 0.f, 0.f}; acc1[0][1] = {0.f, 0.f, 0.f, 0.f};
        acc1[1][0] = {0.f, 0.f, 0.f, 0.f}; acc1[1][1] = {0.f, 0.f, 0.f, 0.f};
#pragma unroll
        for (int kc = 0; kc < 6; kc++) {
#pragma unroll
            for (int ni = 0; ni < 2; ni++) {
                bh8 w = *(const bh8*)&W1s[cur][kc][ni * 16 + l15][quad * 8];
                acc1[0][ni] = mfma_bf16(w, xr[0][kc], acc1[0][ni]);
                acc1[1][ni] = mfma_bf16(w, xr[1][kc], acc1[1][ni]);
            }
        }
#pragma unroll
        for (int rt = 0; rt < 2; rt++) {
#pragma unroll
            for (int ni = 0; ni < 2; ni++) {
                const fx4 bv = ni ? bv1 : bv0;
                sh4 pk;
#pragma unroll
                for (int r = 0; r < 4; r++) {
                    float v = acc1[rt][ni][r] + bv[r];
                    float h = 0.5f * v * (1.0f + fast_erf(v * 0.70710678118654752f));
                    pk[r] = bf16s(h);
                }
                *(sh4*)&Hs[wave * 32 + rt * 16 + l15][ni * 16 + quad * 4] = pk;
            }
        }
        LGKM0;
        bh8 ha0 = *(const bh8*)&Hs[wave * 32 + l15][quad * 8];
        bh8 ha1 = *(const bh8*)&Hs[wave * 32 + 16 + l15][quad * 8];
#pragma unroll
        for (int nt = 0; nt < 12; nt++) {
            bh8 w2 = *(const bh8*)&W2s[cur][nt * 16 + l15][quad * 8];
            acc2[0][nt] = mfma_bf16(ha0, w2, acc2[0][nt]);
            acc2[1][nt] = mfma_bf16(ha1, w2, acc2[1][nt]);
        }
    }

    // ---- epilogue: += b2 + residual (x1 already in out), fp32 in-place ----
#pragma unroll
    for (int rt = 0; rt < 2; rt++)
#pragma unroll
    for (int nt = 0; nt < 12; nt++) {
        const int n = nt * 16 + l15;
        const float bn = b2[n];
#pragma unroll
        for (int r = 0; r < 4; r++) {
            const int m = m0 + wave * 32 + rt * 16 + quad * 4 + r;
            out[(size_t)m * 192 + n] += acc2[rt][nt][r] + bn;
        }
    }
}

// ---------------- proj + residual + LN2 fused: tile 64 x 192 (full row) ----------------
// x1out = A*Wt + pb + xresid (fp32, -> d_out); y2out = LN(x1out)*g2+b2 (bf16)
__global__ __launch_bounds__(256)
void projln_k(const __hip_bfloat16* __restrict__ A,
              const __hip_bfloat16* __restrict__ Bt,
              const float* __restrict__ pb,
              const float* __restrict__ xresid,
              const float* __restrict__ g2,
              const float* __restrict__ b2,
              float* __restrict__ x1out,
              __hip_bfloat16* __restrict__ y2out)
{
    __shared__ __align__(16) __hip_bfloat16 As[64 * 32];    // 4 KB
    __shared__ __align__(16) __hip_bfloat16 Bs[192 * 32];   // 12 KB
    const int tid  = threadIdx.x;
    const int lane = tid & 63, wave = tid >> 6;
    const int quad = lane >> 4, l15 = lane & 15;
    const int m0 = blockIdx.x * 64;

    const int arow = lane >> 2, acol = (lane & 3) * 8;
    const __hip_bfloat16* Ag = A + (size_t)(m0 + wave * 16 + arow) * 192 + acol;
    __hip_bfloat16* Al = &As[(wave * 16) * 32];
    const __hip_bfloat16* Bg0 = Bt + (size_t)((wave + 0) * 16 + arow) * 192 + acol;
    const __hip_bfloat16* Bg1 = Bt + (size_t)((wave + 4) * 16 + arow) * 192 + acol;
    const __hip_bfloat16* Bg2 = Bt + (size_t)((wave + 8) * 16 + arow) * 192 + acol;
    __hip_bfloat16* Bl0 = &Bs[((wave + 0) * 16) * 32];
    __hip_bfloat16* Bl1 = &Bs[((wave + 4) * 16) * 32];
    __hip_bfloat16* Bl2 = &Bs[((wave + 8) * 16) * 32];

    fx4 acc[12];
#pragma unroll
    for (int ct = 0; ct < 12; ct++) acc[ct] = {0.f, 0.f, 0.f, 0.f};

    for (int k0 = 0; k0 < 192; k0 += 32) {
        gload16(Ag  + k0, Al);
        gload16(Bg0 + k0, Bl0);
        gload16(Bg1 + k0, Bl1);
        gload16(Bg2 + k0, Bl2);
        __syncthreads();
        bh8 a = *(const bh8*)&As[(wave * 16 + l15) * 32 + quad * 8];
#pragma unroll
        for (int ct = 0; ct < 12; ct++) {
            bh8 b = *(const bh8*)&Bs[(ct * 16 + l15) * 32 + quad * 8];
            acc[ct] = mfma_bf16(a, b, acc[ct]);
        }
        __syncthreads();
    }

#pragma unroll
    for (int r = 0; r < 4; r++) {
        const int row = m0 + wave * 16 + quad * 4 + r;
        float vv[12];
        float s = 0.f, q = 0.f;
#pragma unroll
        for (int ct = 0; ct < 12; ct++) {
            const int col = ct * 16 + l15;
            float v = acc[ct][r] + pb[col] + xresid[(size_t)row * 192 + col];
            vv[ct] = v;
            x1out[(size_t)row * 192 + col] = v;
            s += v;
            q += v * v;
        }
        s += __shfl_xor(s, 1, 64);  q += __shfl_xor(q, 1, 64);
        s += __shfl_xor(s, 2, 64);  q += __shfl_xor(q, 2, 64);
        s += __shfl_xor(s, 4, 64);  q += __shfl_xor(q, 4, 64);
        s += __shfl_xor(s, 8, 64);  q += __shfl_xor(q, 8, 64);
        float mean = s * (1.0f / 192.0f);
        float var  = q * (1.0f / 192.0f) - mean * mean;
        float rstd = rsqrtf(var + 1e-5f);
#pragma unroll
        for (int ct = 0; ct < 12; ct++) {
            const int col = ct * 16 + l15;
            float y = (vv[ct] - mean) * rstd * g2[col] + b2[col];
            y2out[(size_t)row * 192 + col] = __float2bfloat16(y);
        }
    }
}

// ---------------- attention: one block per (window, head) ----------------
// Vt stride 72 elems (de-conflicted); XCD-chunked block swizzle (verified R10).
__global__ __launch_bounds__(256)
void attn_k(const __hip_bfloat16* __restrict__ qkv,   // [2048][49][576]
            const float* __restrict__ bias_table,
            __hip_bfloat16* __restrict__ aout)        // orig token order
{
    __shared__ __align__(16) __hip_bfloat16 Qb[64 * 32];
    __shared__ __align__(16) __hip_bfloat16 Kb[64 * 32];
    __shared__ __align__(16) __hip_bfloat16 Vt[32 * 72];   // Vt[d][m], stride 72
    __shared__ __align__(16) __hip_bfloat16 Ps[64 * 72];   // padded stride 72
    __shared__ float bias_h[169];

    const int tid  = threadIdx.x;
    const int lane = tid & 63, wave = tid >> 6;
    const int quad = lane >> 4, l15 = lane & 15;
    const int wk = (blockIdx.x & 7) * 1536 + ((int)blockIdx.x >> 3);
    const int w = wk / 6, hd = wk % 6;
    const int b = w >> 6, wrem = w & 63, wi = wrem >> 3, wj = wrem & 7;
    const size_t base = (size_t)w * 49 * 576 + hd * 32;

    if (tid < 169) bias_h[tid] = bias_table[tid * 6 + hd];

    bh8 z = {0, 0, 0, 0, 0, 0, 0, 0};
    {
        int row = tid >> 2, ch = (tid & 3) * 8;
        if (row < 49) {
            *(bh8*)&Qb[row * 32 + ch] = *(const bh8*)(qkv + base + (size_t)row * 576 + ch);
            *(bh8*)&Kb[row * 32 + ch] = *(const bh8*)(qkv + base + (size_t)row * 576 + 192 + ch);
        } else {
            *(bh8*)&Qb[row * 32 + ch] = z;
            *(bh8*)&Kb[row * 32 + ch] = z;
        }
        for (int i = tid; i < 288; i += 256)       // zero all of Vt (32*72/8 units)
            *(bh8*)&Vt[i * 8] = z;
    }
    __syncthreads();
    for (int idx = tid; idx < 49 * 32; idx += 256) {       // V transpose scatter
        int n = idx >> 5, d = idx & 31;
        Vt[d * 72 + n] = qkv[base + (size_t)n * 576 + 384 + d];
    }
    __syncthreads();

    // ---- scores S = Q K^T ----
    fx4 zf = {0.f, 0.f, 0.f, 0.f};
    bh8 aq = *(const bh8*)&Qb[(wave * 16 + l15) * 32 + quad * 8];
    fx4 sarr[4];
#pragma unroll
    for (int ni = 0; ni < 4; ni++) {
        bh8 bk = *(const bh8*)&Kb[(ni * 16 + l15) * 32 + quad * 8];
        sarr[ni] = mfma_bf16(aq, bk, zf);
    }

    // ---- bias + mask + softmax ----
    int iarr[4], ria[4], cia[4], mbi[4];
#pragma unroll
    for (int r = 0; r < 4; r++) {
        int i = wave * 16 + quad * 4 + r;
        int ri = i / 7, ci = i - ri * 7;
        iarr[r] = i; ria[r] = ri; cia[r] = ci;
        int ar = wi * 7 + ri, ac = wj * 7 + ci;
        int br = (ar < 49) ? 0 : ((ar < 53) ? 1 : 2);
        int bc = (ac < 49) ? 0 : ((ac < 53) ? 1 : 2);
        mbi[r] = br * 3 + bc;
    }
    float vals[4][4];   // [ni][r]
#pragma unroll
    for (int ni = 0; ni < 4; ni++) {
        int jcol = ni * 16 + l15;
        int rj = jcol / 7, cj = jcol - rj * 7;
        int ar = wi * 7 + rj, ac = wj * 7 + cj;
        int br = (ar < 49) ? 0 : ((ar < 53) ? 1 : 2);
        int bc = (ac < 49) ? 0 : ((ac < 53) ? 1 : 2);
        int mbj = br * 3 + bc;
#pragma unroll
        for (int r = 0; r < 4; r++) {
            float v;
            if (jcol >= 49)            v = -1e30f;
            else if (iarr[r] >= 49)    v = 0.0f;
            else {
                int bidx = (ria[r] - rj + 6) * 13 + (cia[r] - cj + 6);
                v = sarr[ni][r] + bias_h[bidx] + ((mbi[r] != mbj) ? -100.0f : 0.0f);
            }
            vals[ni][r] = v;
        }
    }
#pragma unroll
    for (int r = 0; r < 4; r++) {
        float mx = fmaxf(fmaxf(vals[0][r], vals[1][r]), fmaxf(vals[2][r], vals[3][r]));
        mx = fmaxf(mx, __shfl_xor(mx, 1, 64));
        mx = fmaxf(mx, __shfl_xor(mx, 2, 64));
        mx = fmaxf(mx, __shfl_xor(mx, 4, 64));
        mx = fmaxf(mx, __shfl_xor(mx, 8, 64));
        float e0 = __expf(vals[0][r] - mx);
        float e1 = __expf(vals[1][r] - mx);
        float e2 = __expf(vals[2][r] - mx);
        float e3 = __expf(vals[3][r] - mx);
        float sm = e0 + e1 + e2 + e3;
        sm += __shfl_xor(sm, 1, 64);
        sm += __shfl_xor(sm, 2, 64);
        sm += __shfl_xor(sm, 4, 64);
        sm += __shfl_xor(sm, 8, 64);
        float inv = 1.0f / sm;
        int prow = (wave * 16 + quad * 4 + r) * 72;
        Ps[prow + 0 * 16 + l15] = __float2bfloat16(e0 * inv);
        Ps[prow + 1 * 16 + l15] = __float2bfloat16(e1 * inv);
        Ps[prow + 2 * 16 + l15] = __float2bfloat16(e2 * inv);
        Ps[prow + 3 * 16 + l15] = __float2bfloat16(e3 * inv);
    }
    __syncthreads();

    // ---- O = P V ----
    fx4 o0 = zf, o1 = zf;
#pragma unroll
    for (int k0 = 0; k0 < 64; k0 += 32) {
        bh8 ap  = *(const bh8*)&Ps[(wave * 16 + l15) * 72 + k0 + quad * 8];
        bh8 bv0 = *(const bh8*)&Vt[(l15)      * 72 + k0 + quad * 8];
        bh8 bv1 = *(const bh8*)&Vt[(16 + l15) * 72 + k0 + quad * 8];
        o0 = mfma_bf16(ap, bv0, o0);
        o1 = mfma_bf16(ap, bv1, o1);
    }

    // ---- write out in ORIGINAL token order ----
#pragma unroll
    for (int r = 0; r < 4; r++) {
        int m = wave * 16 + quad * 4 + r;
        if (m < 49) {
            int i = m / 7, j2 = m - i * 7;
            int orow = wi * 7 + i + 3;  if (orow >= 56) orow -= 56;
            int ocol = wj * 7 + j2 + 3; if (ocol >= 56) ocol -= 56;
            size_t t = (size_t)b * 3136 + orow * 56 + ocol;
            aout[t * 192 + hd * 32 + l15]      = __float2bfloat16(o0[r]);
            aout[t * 192 + hd * 32 + 16 + l15] = __float2bfloat16(o1[r]);
        }
    }
}

// ---------------- launch ----------------
// Layout (peak 193.6 MB):
//   buf1 @ 0          38,535,168 B : attn_out (orig order) -> y2
//   buf2 @ 38,535,168 154,140,672 B: qkv full (115.6 MB)
//   weights @ 192,675,840 .. 193,560,576
//   x1 lives in d_out (fp32); mlp_k does in-place owner-computes residual add on d_out.
extern "C" void kernel_launch(void* const* d_in, const int* in_sizes, int n_in,
                              void* d_out, int out_size, void* d_ws, size_t ws_size,
                              hipStream_t stream)
{
    const float* x      = (const float*)d_in[0];
    const float* n1g    = (const float*)d_in[1];
    const float* n1b    = (const float*)d_in[2];
    const float* qkv_w  = (const float*)d_in[3];
    const float* qkv_b  = (const float*)d_in[4];
    const float* proj_w = (const float*)d_in[5];
    const float* proj_b = (const float*)d_in[6];
    const float* btab   = (const float*)d_in[7];
    const float* n2g    = (const float*)d_in[8];
    const float* n2b    = (const float*)d_in[9];
    const float* fc1_w  = (const float*)d_in[10];
    const float* fc1_b  = (const float*)d_in[11];
    const float* fc2_w  = (const float*)d_in[12];
    const float* fc2_b  = (const float*)d_in[13];

    char* ws = (char*)d_ws;
    __hip_bfloat16* buf1    = (__hip_bfloat16*)(ws + 0);           // 38,535,168 B
    __hip_bfloat16* buf2    = (__hip_bfloat16*)(ws + 38535168);    // 154,140,672 B
    __hip_bfloat16* wt_qkv  = (__hip_bfloat16*)(ws + 192675840);   // 221,184 B
    __hip_bfloat16* wt_proj = (__hip_bfloat16*)(ws + 192897024);   // 73,728 B
    __hip_bfloat16* wt_fc1  = (__hip_bfloat16*)(ws + 192970752);   // 294,912 B
    __hip_bfloat16* wt_fc2  = (__hip_bfloat16*)(ws + 193265664);   // 294,912 B
    float*          x1      = (float*)d_out;                       // 77,070,336 B

    // all 4 weight converts in one launch (442368 elems)
    convw_all_k<<<dim3(1728), 256, 0, stream>>>(qkv_w, proj_w, fc1_w, fc2_w,
                                                wt_qkv, wt_proj, wt_fc1, wt_fc2);

    // fused LN1 + shift/gather + QKV GEMM: x -> buf2 (bf16 qkv, window order)
    lnqkv_k<<<dim3(1568), 256, 0, stream>>>(x, n1g, n1b, wt_qkv, qkv_b, buf2);

    // attention: 2048 windows x 6 heads -> buf1 (bf16, orig token order)
    attn_k<<<dim3(12288), 256, 0, stream>>>(buf2, btab, buf1);

    // proj + residual + LN2: x1 -> d_out (fp32), y2 -> buf1 (bf16, in-place over attn_out)
    projln_k<<<dim3(1568), 256, 0, stream>>>(buf1, wt_proj, proj_b, x, n2g, n2b, x1, buf1);

    // fused FC1 + gelu + FC2 + residual (in-place on d_out), 128 rows/block
    mlp_k<<<dim3(784), 256, 0, stream>>>(buf1, wt_fc1, wt_fc2, fc1_b, fc2_b, x1);
}